// Round 1
// baseline (63.194 us; speedup 1.0000x reference)
//
#include <hip/hip_runtime.h>

// Problem constants (from reference): B=4, Q=512, K=512, F=128.
// Key insight: softmax over the singleton last dim == exactly 1.0, so
//   out[b,q,d] = sum_k values[b,k,d]   (independent of q, queries, keys, w_score)
// One kernel: per-batch column sum of values, broadcast over Q.

#define BD 4
#define QD 512
#define KD 512
#define FD 128
#define F4 (FD / 4)                    // 32 float4 per row
#define QROWS_PER_BLK 16
#define BLKS_PER_B (QD / QROWS_PER_BLK) // 32 blocks per batch

__global__ __launch_bounds__(256) void AdditiveAttention_colsum_bcast(
    const float* __restrict__ values, float* __restrict__ out) {
    const int blk = blockIdx.x;
    const int b   = blk / BLKS_PER_B;
    const int qc  = blk % BLKS_PER_B;
    const int tid = threadIdx.x;
    const int col = tid & (F4 - 1);   // 0..31  (float4 column within F)
    const int rg  = tid >> 5;         // 0..7   (row group)

    const float4* __restrict__ V4 =
        reinterpret_cast<const float4*>(values + (size_t)b * KD * FD);

    // Each thread sums 64 of the 512 K-rows for its float4 column.
    float4 acc = make_float4(0.f, 0.f, 0.f, 0.f);
    #pragma unroll 8
    for (int k = rg; k < KD; k += 8) {
        float4 v = V4[k * F4 + col];
        acc.x += v.x; acc.y += v.y; acc.z += v.z; acc.w += v.w;
    }

    // Reduce the 8 row-groups in LDS (4 KiB).
    __shared__ float4 red[8][F4];
    red[rg][col] = acc;
    __syncthreads();
    #pragma unroll
    for (int s = 4; s >= 1; s >>= 1) {
        if (rg < s) {
            float4 a = red[rg][col];
            float4 o = red[rg + s][col];
            a.x += o.x; a.y += o.y; a.z += o.z; a.w += o.w;
            red[rg][col] = a;
        }
        __syncthreads();
    }
    const float4 sum = red[0][col];

    // Broadcast to this block's 16 q-rows (8 rows per pass, 2 passes).
    float4* __restrict__ O4 =
        reinterpret_cast<float4*>(out + (size_t)b * QD * FD);
    const int qbase = qc * QROWS_PER_BLK;
    #pragma unroll
    for (int i = 0; i < QROWS_PER_BLK; i += 8) {
        const int q = qbase + i + rg;
        O4[q * F4 + col] = sum;
    }
}

extern "C" void kernel_launch(void* const* d_in, const int* in_sizes, int n_in,
                              void* d_out, int out_size, void* d_ws, size_t ws_size,
                              hipStream_t stream) {
    // inputs: 0=queries (unused), 1=keys (unused), 2=values, 3=w_score (unused)
    const float* values = (const float*)d_in[2];
    float* out = (float*)d_out;
    AdditiveAttention_colsum_bcast<<<BD * BLKS_PER_B, 256, 0, stream>>>(values, out);
}

// Round 2
// 63.173 us; speedup vs baseline: 1.0003x; 1.0003x over previous
//
#include <hip/hip_runtime.h>

// Problem constants (from reference): B=4, Q=512, K=512, F=128.
// Key insight: softmax over the singleton last dim == exactly 1.0, so
//   out[b,q,d] = sum_k values[b,k,d]   (independent of q, queries, keys, w_score)
// One kernel: per-batch column sum of values, broadcast over Q.
//
// R1 -> R2: 128 blocks x 256 thr (64-row chain/thread) -> 256 blocks x 512 thr
// (32-row chain/thread). All 256 CUs occupied; dependent-load chain halved.

#define BD 4
#define QD 512
#define KD 512
#define FD 128
#define F4 (FD / 4)                     // 32 float4 per row
#define QROWS_PER_BLK 8
#define BLKS_PER_B (QD / QROWS_PER_BLK) // 64 blocks per batch
#define NRG 16                          // row groups (512 thr / 32 cols)

__global__ __launch_bounds__(512) void AdditiveAttention_colsum_bcast(
    const float* __restrict__ values, float* __restrict__ out) {
    const int blk = blockIdx.x;
    const int b   = blk / BLKS_PER_B;
    const int qc  = blk % BLKS_PER_B;
    const int tid = threadIdx.x;
    const int col = tid & (F4 - 1);   // 0..31  (float4 column within F)
    const int rg  = tid >> 5;         // 0..15  (row group)

    const float4* __restrict__ V4 =
        reinterpret_cast<const float4*>(values + (size_t)b * KD * FD);

    // Each thread sums 32 of the 512 K-rows for its float4 column.
    float4 acc = make_float4(0.f, 0.f, 0.f, 0.f);
    #pragma unroll 8
    for (int k = rg; k < KD; k += NRG) {
        float4 v = V4[k * F4 + col];
        acc.x += v.x; acc.y += v.y; acc.z += v.z; acc.w += v.w;
    }

    // Reduce the 16 row-groups in LDS (8 KiB).
    __shared__ float4 red[NRG][F4];
    red[rg][col] = acc;
    __syncthreads();
    #pragma unroll
    for (int s = NRG / 2; s >= 1; s >>= 1) {
        if (rg < s) {
            float4 a = red[rg][col];
            float4 o = red[rg + s][col];
            a.x += o.x; a.y += o.y; a.z += o.z; a.w += o.w;
            red[rg][col] = a;
        }
        __syncthreads();
    }
    const float4 sum = red[0][col];

    // Broadcast to this block's 8 q-rows (row groups 0..7 write one row each).
    float4* __restrict__ O4 =
        reinterpret_cast<float4*>(out + (size_t)b * QD * FD);
    const int qbase = qc * QROWS_PER_BLK;
    if (rg < QROWS_PER_BLK) {
        O4[(qbase + rg) * F4 + col] = sum;
    }
}

extern "C" void kernel_launch(void* const* d_in, const int* in_sizes, int n_in,
                              void* d_out, int out_size, void* d_ws, size_t ws_size,
                              hipStream_t stream) {
    // inputs: 0=queries (unused), 1=keys (unused), 2=values, 3=w_score (unused)
    const float* values = (const float*)d_in[2];
    float* out = (float*)d_out;
    AdditiveAttention_colsum_bcast<<<BD * BLKS_PER_B, 512, 0, stream>>>(values, out);
}